// Round 1
// baseline (110.372 us; speedup 1.0000x reference)
//
#include <hip/hip_runtime.h>
#include <math.h>

namespace {

constexpr int KK = 4;
constexpr int DD = 16;
constexpr int BLOCK = 256;
constexpr int PTS = 4;                       // points per thread
constexpr float LOG2PI = 1.8378770664093453f;

__global__ __launch_bounds__(BLOCK)
void gmm_energy(const float* __restrict__ z, const float* __restrict__ phi,
                const float* __restrict__ mu, const float* __restrict__ L,
                float* __restrict__ out, int N)
{
    __shared__ float sLinv[KK][DD][DD];   // inverse of upper-triangular L_k (zeros below diag)
    __shared__ float sW[KK][DD];          // w_k = Linv_k * mu_k
    __shared__ float sC0[KK];             // log(phi_k) - 0.5*D*log(2pi) - logdet

    const int tid = threadIdx.x;

    // ---- per-block prep: invert the 4 upper-triangular 16x16 factors ----
    // thread (k,j) computes column j of Linv_k via predicated, fixed-trip
    // back substitution (fully unrolled -> registers only, no scratch).
    if (tid < KK * DD) {
        const int k = tid >> 4;
        const int j = tid & 15;
        const float* Lk = L + k * DD * DD;
        float xv[DD];
        #pragma unroll
        for (int m = 0; m < DD; ++m) xv[m] = 0.0f;
        #pragma unroll
        for (int i = DD - 1; i >= 0; --i) {
            float s = (i == j) ? 1.0f : 0.0f;
            #pragma unroll
            for (int m = i + 1; m < DD; ++m)
                s -= Lk[i * DD + m] * xv[m];          // xv[m]==0 for m>j
            xv[i] = (i <= j) ? (s / Lk[i * DD + i]) : 0.0f;
        }
        #pragma unroll
        for (int i = 0; i < DD; ++i)
            sLinv[k][i][j] = xv[i];
    }
    __syncthreads();
    if (tid < KK * DD) {
        const int k = tid >> 4;
        const int i = tid & 15;
        float w = 0.0f;
        #pragma unroll
        for (int j = 0; j < DD; ++j)
            w += sLinv[k][i][j] * mu[k * DD + j];
        sW[k][i] = w;
    }
    if (tid < KK) {
        float logdet = 0.0f;
        #pragma unroll
        for (int i = 0; i < DD; ++i)
            logdet += __logf(L[tid * DD * DD + i * DD + i]);
        sC0[tid] = __logf(phi[tid]) - 8.0f * LOG2PI - logdet;
    }
    __syncthreads();

    const int base = blockIdx.x * (BLOCK * PTS) + tid * PTS;

    // ---- load 4 rows of z (each row = 64 B, four float4 loads) ----
    float zr[PTS][DD];
    if (base + PTS <= N) {
        #pragma unroll
        for (int p = 0; p < PTS; ++p) {
            const float4* zp = reinterpret_cast<const float4*>(z + (size_t)(base + p) * DD);
            #pragma unroll
            for (int c = 0; c < 4; ++c) {
                float4 v = zp[c];
                zr[p][c * 4 + 0] = v.x;
                zr[p][c * 4 + 1] = v.y;
                zr[p][c * 4 + 2] = v.z;
                zr[p][c * 4 + 3] = v.w;
            }
        }
    } else {
        #pragma unroll
        for (int p = 0; p < PTS; ++p) {
            if (base + p < N) {
                const float4* zp = reinterpret_cast<const float4*>(z + (size_t)(base + p) * DD);
                #pragma unroll
                for (int c = 0; c < 4; ++c) {
                    float4 v = zp[c];
                    zr[p][c * 4 + 0] = v.x;
                    zr[p][c * 4 + 1] = v.y;
                    zr[p][c * 4 + 2] = v.z;
                    zr[p][c * 4 + 3] = v.w;
                }
            } else {
                #pragma unroll
                for (int d = 0; d < DD; ++d) zr[p][d] = 0.0f;
            }
        }
    }

    // ---- per-component Mahalanobis via triangular matvec ----
    float lg[PTS][KK];
    #pragma unroll
    for (int k = 0; k < KK; ++k) {
        float q[PTS];
        #pragma unroll
        for (int p = 0; p < PTS; ++p) q[p] = 0.0f;
        #pragma unroll
        for (int i = 0; i < DD; ++i) {
            const float wk = sW[k][i];
            float acc[PTS];
            #pragma unroll
            for (int p = 0; p < PTS; ++p) acc[p] = -wk;
            #pragma unroll
            for (int j = i; j < DD; ++j) {
                const float cf = sLinv[k][i][j];   // wave-uniform LDS broadcast
                #pragma unroll
                for (int p = 0; p < PTS; ++p)
                    acc[p] = fmaf(cf, zr[p][j], acc[p]);
            }
            #pragma unroll
            for (int p = 0; p < PTS; ++p)
                q[p] = fmaf(acc[p], acc[p], q[p]);
        }
        const float c0 = sC0[k];
        #pragma unroll
        for (int p = 0; p < PTS; ++p)
            lg[p][k] = fmaf(-0.5f, q[p], c0);
    }

    // ---- logsumexp over K=4, negate, store ----
    float e[PTS];
    #pragma unroll
    for (int p = 0; p < PTS; ++p) {
        float m01 = fmaxf(lg[p][0], lg[p][1]);
        float m23 = fmaxf(lg[p][2], lg[p][3]);
        float m = fmaxf(m01, m23);
        float s = __expf(lg[p][0] - m) + __expf(lg[p][1] - m)
                + __expf(lg[p][2] - m) + __expf(lg[p][3] - m);
        e[p] = -(m + __logf(s));
    }

    if (base + PTS <= N) {
        float4 res;
        res.x = e[0]; res.y = e[1]; res.z = e[2]; res.w = e[3];
        *reinterpret_cast<float4*>(out + base) = res;
    } else {
        #pragma unroll
        for (int p = 0; p < PTS; ++p) {
            if (base + p < N) out[base + p] = e[p];
        }
    }
}

} // namespace

extern "C" void kernel_launch(void* const* d_in, const int* in_sizes, int n_in,
                              void* d_out, int out_size, void* d_ws, size_t ws_size,
                              hipStream_t stream) {
    const float* z   = (const float*)d_in[0];   // [N,16]
    const float* phi = (const float*)d_in[1];   // [4]
    const float* mu  = (const float*)d_in[2];   // [4,16]
    const float* L   = (const float*)d_in[3];   // [4,16,16] upper-triangular
    float* out = (float*)d_out;                 // [N]
    const int N = in_sizes[0] / DD;
    const int grid = (N + BLOCK * PTS - 1) / (BLOCK * PTS);
    gmm_energy<<<grid, BLOCK, 0, stream>>>(z, phi, mu, L, out, N);
}